// Round 19
// baseline (2136.441 us; speedup 1.0000x reference)
//
#include <hip/hip_runtime.h>
#include <hip/hip_bf16.h>
#include <stdint.h>

typedef __bf16 bf16;
typedef __bf16 bf16x8 __attribute__((ext_vector_type(8)));
typedef float f32x4 __attribute__((ext_vector_type(4)));
typedef float f32x8u __attribute__((ext_vector_type(8)));
typedef f32x8u f32x8a __attribute__((aligned(4)));

// async global->LDS, 16B per lane; LDS dest = wave-uniform base + lane*16
__device__ __forceinline__ void gl16(const void* g, void* lds) {
  __builtin_amdgcn_global_load_lds(
      (const __attribute__((address_space(1))) void*)g,
      (__attribute__((address_space(3))) void*)lds, 16, 0, 0);
}

// ---------------------------------------------------------------------------
// gemm_hr: 128x128 tile, 1-phase, 16x16x32 (proven). Split-storage emulated-
// fp32 GEMM, BT form: C[m,n] = sum_k A[m,k]*B[n,k], acc += AhBh + AhBr + ArBh.
// Used for qk (grid 256 = good fill) and the small G GEMM.
// OUT: 0 fp32, 1 h/r planes.
// ---------------------------------------------------------------------------
template <int OUT>
__global__ __launch_bounds__(256) void gemm_hr(
    const bf16* __restrict__ Ah, const bf16* __restrict__ Ar, int lda,
    long long sA_, const bf16* __restrict__ Bh, const bf16* __restrict__ Br,
    int ldb, long long sB_, float* __restrict__ Cf, bf16* __restrict__ Ch,
    bf16* __restrict__ Cr, int ldc, long long sC_, int N, int K, int ntn) {
  __shared__ bf16 tAh[128][32], tAr[128][32], tBh[128][32], tBr[128][32];

  const int tid = threadIdx.x;
  const int lane = tid & 63, wave = tid >> 6;
  const int wm = wave & 1, wn = wave >> 1;
  const int fr = lane & 15, fq = lane >> 4;

  const long long bz = blockIdx.y;
  Ah += bz * sA_;
  Ar += bz * sA_;
  Bh += bz * sB_;
  Br += bz * sB_;

  const int cpx = gridDim.x >> 3;
  const int b2 = (blockIdx.x & 7) * cpx + (blockIdx.x >> 3);
  const int tm = b2 / ntn, tn = b2 % ntn;
  const int m0 = tm * 128, n0 = tn * 128;

  const int c0 = wave * 128 + lane;
  const int colsw = (((c0 & 3) ^ ((c0 >> 3) & 3)) << 3);
  const int rA0 = m0 + (c0 >> 2);
  int rB0 = n0 + (c0 >> 2), rB1 = rB0 + 16;
  rB0 = rB0 < N ? rB0 : N - 1;
  rB1 = rB1 < N ? rB1 : N - 1;
  const long long offA0 = (long long)rA0 * lda + colsw;
  const long long offA1 = offA0 + (long long)16 * lda;
  const long long offB0 = (long long)rB0 * ldb + colsw;
  const long long offB1 = (long long)rB1 * ldb + colsw;

  char* dAh = (char*)&tAh[0][0] + wave * 2048;
  char* dAr = (char*)&tAr[0][0] + wave * 2048;
  char* dBh = (char*)&tBh[0][0] + wave * 2048;
  char* dBr = (char*)&tBr[0][0] + wave * 2048;

  const int colA = ((fq ^ ((fr >> 1) & 3)) << 3);

  f32x4 acc[4][4] = {};
  const int nk = K >> 5;
  for (int kt = 0; kt < nk; ++kt) {
    const int k0 = kt << 5;
    gl16(Ah + offA0 + k0, dAh);
    gl16(Ah + offA1 + k0, dAh + 1024);
    gl16(Ar + offA0 + k0, dAr);
    gl16(Ar + offA1 + k0, dAr + 1024);
    gl16(Bh + offB0 + k0, dBh);
    gl16(Bh + offB1 + k0, dBh + 1024);
    gl16(Br + offB0 + k0, dBr);
    gl16(Br + offB1 + k0, dBr + 1024);
    __syncthreads();  // drains vmcnt(0): LDS tiles ready

    bf16x8 ah[4], ar_[4], bh[4], br_[4];
#pragma unroll
    for (int i = 0; i < 4; ++i) {
      ah[i] = *reinterpret_cast<const bf16x8*>(&tAh[wm * 64 + i * 16 + fr][colA]);
      ar_[i] = *reinterpret_cast<const bf16x8*>(&tAr[wm * 64 + i * 16 + fr][colA]);
      bh[i] = *reinterpret_cast<const bf16x8*>(&tBh[wn * 64 + i * 16 + fr][colA]);
      br_[i] = *reinterpret_cast<const bf16x8*>(&tBr[wn * 64 + i * 16 + fr][colA]);
    }
#pragma unroll
    for (int mi = 0; mi < 4; ++mi)
#pragma unroll
      for (int ni = 0; ni < 4; ++ni)
        acc[mi][ni] = __builtin_amdgcn_mfma_f32_16x16x32_bf16(
            ah[mi], bh[ni], acc[mi][ni], 0, 0, 0);
#pragma unroll
    for (int mi = 0; mi < 4; ++mi)
#pragma unroll
      for (int ni = 0; ni < 4; ++ni)
        acc[mi][ni] = __builtin_amdgcn_mfma_f32_16x16x32_bf16(
            ah[mi], br_[ni], acc[mi][ni], 0, 0, 0);
#pragma unroll
    for (int mi = 0; mi < 4; ++mi)
#pragma unroll
      for (int ni = 0; ni < 4; ++ni)
        acc[mi][ni] = __builtin_amdgcn_mfma_f32_16x16x32_bf16(
            ar_[mi], bh[ni], acc[mi][ni], 0, 0, 0);
    __syncthreads();
  }

  if constexpr (OUT == 0) {
    float* C = Cf + bz * sC_;
#pragma unroll
    for (int mi = 0; mi < 4; ++mi)
#pragma unroll
      for (int ni = 0; ni < 4; ++ni) {
        int cc = n0 + wn * 64 + ni * 16 + fr;
        if (cc < N) {
          long long base = (long long)(m0 + wm * 64 + mi * 16 + fq * 4) * ldc + cc;
#pragma unroll
          for (int j = 0; j < 4; ++j) C[base + (long long)j * ldc] = acc[mi][ni][j];
        }
      }
  } else {
    bf16* CH = Ch + bz * sC_;
    bf16* CR = Cr + bz * sC_;
#pragma unroll
    for (int mi = 0; mi < 4; ++mi)
#pragma unroll
      for (int ni = 0; ni < 4; ++ni) {
        int cc = n0 + wn * 64 + ni * 16 + fr;
        if (cc < N) {
          long long base = (long long)(m0 + wm * 64 + mi * 16 + fq * 4) * ldc + cc;
#pragma unroll
          for (int j = 0; j < 4; ++j) {
            float v = acc[mi][ni][j];
            bf16 h = (bf16)v;
            CH[base + (long long)j * ldc] = h;
            CR[base + (long long)j * ldc] = (bf16)(v - (float)h);
          }
        }
      }
  }
}

// ---------------------------------------------------------------------------
// gemm_hr2: 256x128 tile, 4 waves of 128x64, 1-phase, 16x16x32 (proven).
// M param: A rows (staging reads clamped to M-1; stores guarded) -> supports
// padded-M launches (vT swap, M=1056). ntn > 0: tm-major (tm=b2/ntn);
// ntn < 0: tn-major with |ntn| = ntm (tm=b2%ntm) — co-locates B-panel
// sharers on one XCD when A is small/L2-resident.
// OUT: 0 fp32 C; 1 h/r C; 2 h/r C transposed.
// XCD swizzle: bijective for ANY gridDim.x (m204 form).
// ---------------------------------------------------------------------------
template <int OUT>
__global__ __launch_bounds__(256, 2) void gemm_hr2(
    const bf16* __restrict__ Ah, const bf16* __restrict__ Ar, int lda,
    long long sA_, const bf16* __restrict__ Bh, const bf16* __restrict__ Br,
    int ldb, long long sB_, float* __restrict__ Cf, bf16* __restrict__ Ch,
    bf16* __restrict__ Cr, int ldc, long long sC_, int M, int N, int K,
    int ntn) {
  __shared__ bf16 tAh[256][32], tAr[256][32], tBh[128][32], tBr[128][32];

  const int tid = threadIdx.x;
  const int lane = tid & 63, wave = tid >> 6;
  const int wm = wave & 1, wn = wave >> 1;
  const int fr = lane & 15, fq = lane >> 4;

  const long long bz = blockIdx.y;
  Ah += bz * sA_;
  Ar += bz * sA_;
  Bh += bz * sB_;
  Br += bz * sB_;

  // bijective XCD swizzle for arbitrary nwg (m204)
  const int nwg = gridDim.x;
  const int q = nwg >> 3, r = nwg & 7;
  const int xcd = blockIdx.x & 7, o8 = blockIdx.x >> 3;
  const int b2 = (xcd < r ? xcd * (q + 1) : r * (q + 1) + (xcd - r) * q) + o8;
  int tm, tn;
  if (ntn > 0) {
    tm = b2 / ntn;
    tn = b2 % ntn;
  } else {
    const int ntm = -ntn;
    tn = b2 / ntm;
    tm = b2 % ntm;
  }
  const int m0 = tm * 256, n0 = tn * 128;

  const int cA = wave * 64 + lane;
  const int colsw = (((cA & 3) ^ ((cA >> 3) & 3)) << 3);
  const int rA = cA >> 2;  // 0..63
  long long offAj[4];
#pragma unroll
  for (int j = 0; j < 4; ++j) {
    int rAj = m0 + rA + j * 64;
    rAj = rAj < M ? rAj : M - 1;  // clamp padded-M reads
    offAj[j] = (long long)rAj * lda + colsw;
  }
  int rB0 = n0 + rA, rB1 = n0 + rA + 64;
  rB0 = rB0 < N ? rB0 : N - 1;
  rB1 = rB1 < N ? rB1 : N - 1;
  const long long offB0 = (long long)rB0 * ldb + colsw;
  const long long offB1 = (long long)rB1 * ldb + colsw;

  char* dAh = (char*)&tAh[0][0] + wave * 1024;
  char* dAr = (char*)&tAr[0][0] + wave * 1024;
  char* dBh = (char*)&tBh[0][0] + wave * 1024;
  char* dBr = (char*)&tBr[0][0] + wave * 1024;

  const int colA = ((fq ^ ((fr >> 1) & 3)) << 3);

  f32x4 acc[8][4] = {};
  const int nk = K >> 5;
  for (int kt = 0; kt < nk; ++kt) {
    const int k0 = kt << 5;
#pragma unroll
    for (int j = 0; j < 4; ++j) {
      gl16(Ah + offAj[j] + k0, dAh + j * 4096);
      gl16(Ar + offAj[j] + k0, dAr + j * 4096);
    }
    gl16(Bh + offB0 + k0, dBh);
    gl16(Bh + offB1 + k0, dBh + 4096);
    gl16(Br + offB0 + k0, dBr);
    gl16(Br + offB1 + k0, dBr + 4096);
    __syncthreads();  // drains vmcnt(0): tiles ready

    bf16x8 bh[4], br_[4];
#pragma unroll
    for (int i = 0; i < 4; ++i) {
      bh[i] = *reinterpret_cast<const bf16x8*>(&tBh[wn * 64 + i * 16 + fr][colA]);
      br_[i] = *reinterpret_cast<const bf16x8*>(&tBr[wn * 64 + i * 16 + fr][colA]);
    }
#pragma unroll
    for (int mi = 0; mi < 8; ++mi) {
      bf16x8 ah = *reinterpret_cast<const bf16x8*>(
          &tAh[wm * 128 + mi * 16 + fr][colA]);
      bf16x8 ar_ = *reinterpret_cast<const bf16x8*>(
          &tAr[wm * 128 + mi * 16 + fr][colA]);
#pragma unroll
      for (int ni = 0; ni < 4; ++ni)
        acc[mi][ni] = __builtin_amdgcn_mfma_f32_16x16x32_bf16(
            ah, bh[ni], acc[mi][ni], 0, 0, 0);
#pragma unroll
      for (int ni = 0; ni < 4; ++ni)
        acc[mi][ni] = __builtin_amdgcn_mfma_f32_16x16x32_bf16(
            ah, br_[ni], acc[mi][ni], 0, 0, 0);
#pragma unroll
      for (int ni = 0; ni < 4; ++ni)
        acc[mi][ni] = __builtin_amdgcn_mfma_f32_16x16x32_bf16(
            ar_, bh[ni], acc[mi][ni], 0, 0, 0);
    }
    __syncthreads();  // protect LDS before next stage
  }

  if constexpr (OUT == 0) {
    float* C = Cf + bz * sC_;
#pragma unroll
    for (int mi = 0; mi < 8; ++mi)
#pragma unroll
      for (int ni = 0; ni < 4; ++ni) {
        int cc = n0 + wn * 64 + ni * 16 + fr;
        int gr = m0 + wm * 128 + mi * 16 + fq * 4;
        if (cc < N && gr < M) {
          long long base = (long long)gr * ldc + cc;
#pragma unroll
          for (int j = 0; j < 4; ++j) C[base + (long long)j * ldc] = acc[mi][ni][j];
        }
      }
  } else if constexpr (OUT == 1) {
    bf16* CH = Ch + bz * sC_;
    bf16* CR = Cr + bz * sC_;
#pragma unroll
    for (int mi = 0; mi < 8; ++mi)
#pragma unroll
      for (int ni = 0; ni < 4; ++ni) {
        int cc = n0 + wn * 64 + ni * 16 + fr;
        int gr = m0 + wm * 128 + mi * 16 + fq * 4;
        if (cc < N && gr < M) {
          long long base = (long long)gr * ldc + cc;
#pragma unroll
          for (int j = 0; j < 4; ++j) {
            float v = acc[mi][ni][j];
            bf16 h = (bf16)v;
            CH[base + (long long)j * ldc] = h;
            CR[base + (long long)j * ldc] = (bf16)(v - (float)h);
          }
        }
      }
  } else {
    bf16* CH = Ch + bz * sC_;
    bf16* CR = Cr + bz * sC_;
#pragma unroll
    for (int mi = 0; mi < 8; ++mi)
#pragma unroll
      for (int ni = 0; ni < 4; ++ni) {
        int cc = n0 + wn * 64 + ni * 16 + fr;
        int mr = m0 + wm * 128 + mi * 16 + fq * 4;
        if (cc < N && mr < M) {
          union { bf16 h[4]; uint2 u; } th, tr;
#pragma unroll
          for (int j = 0; j < 4; ++j) {
            float v = acc[mi][ni][j];
            bf16 h = (bf16)v;
            th.h[j] = h;
            tr.h[j] = (bf16)(v - (float)h);
          }
          *reinterpret_cast<uint2*>(CH + (long long)cc * ldc + mr) = th.u;
          *reinterpret_cast<uint2*>(CR + (long long)cc * ldc + mr) = tr.u;
        }
      }
  }
}

// ---------------------------------------------------------------------------
// gemm_dot1: layer-3 fast path. 1-pass h-plane GEMM (Ph3 @ a2Th^T) with
// fused dot-with-G epilogue -> one scalar per block.
// ---------------------------------------------------------------------------
__global__ __launch_bounds__(256, 2) void gemm_dot1(
    const bf16* __restrict__ Ah, int lda, long long sA_,
    const bf16* __restrict__ Bh, int ldb, long long sB_, int N, int K,
    int ntn, const float* __restrict__ G, int ldg,
    float* __restrict__ partial) {
  __shared__ bf16 tAh[256][32], tBh[128][32];

  const int tid = threadIdx.x;
  const int lane = tid & 63, wave = tid >> 6;
  const int wm = wave & 1, wn = wave >> 1;
  const int fr = lane & 15, fq = lane >> 4;

  const long long bz = blockIdx.y;
  Ah += bz * sA_;
  Bh += bz * sB_;

  const int nwg = gridDim.x;
  const int q = nwg >> 3, r = nwg & 7;
  const int xcd = blockIdx.x & 7, o8 = blockIdx.x >> 3;
  const int b2 = (xcd < r ? xcd * (q + 1) : r * (q + 1) + (xcd - r) * q) + o8;
  const int tm = b2 / ntn, tn = b2 % ntn;
  const int m0 = tm * 256, n0 = tn * 128;

  const int cA = wave * 64 + lane;
  const int colsw = (((cA & 3) ^ ((cA >> 3) & 3)) << 3);
  const int rA = cA >> 2;
  const long long offA = (long long)(m0 + rA) * lda + colsw;
  const long long strA = (long long)64 * lda;
  int rB0 = n0 + rA, rB1 = n0 + rA + 64;
  rB0 = rB0 < N ? rB0 : N - 1;
  rB1 = rB1 < N ? rB1 : N - 1;
  const long long offB0 = (long long)rB0 * ldb + colsw;
  const long long offB1 = (long long)rB1 * ldb + colsw;

  char* dAh = (char*)&tAh[0][0] + wave * 1024;
  char* dBh = (char*)&tBh[0][0] + wave * 1024;

  const int colA = ((fq ^ ((fr >> 1) & 3)) << 3);

  f32x4 acc[8][4] = {};
  const int nk = K >> 5;
  for (int kt = 0; kt < nk; ++kt) {
    const int k0 = kt << 5;
#pragma unroll
    for (int j = 0; j < 4; ++j) gl16(Ah + offA + j * strA + k0, dAh + j * 4096);
    gl16(Bh + offB0 + k0, dBh);
    gl16(Bh + offB1 + k0, dBh + 4096);
    __syncthreads();

    bf16x8 bh[4];
#pragma unroll
    for (int i = 0; i < 4; ++i)
      bh[i] = *reinterpret_cast<const bf16x8*>(&tBh[wn * 64 + i * 16 + fr][colA]);
#pragma unroll
    for (int mi = 0; mi < 8; ++mi) {
      bf16x8 ah = *reinterpret_cast<const bf16x8*>(
          &tAh[wm * 128 + mi * 16 + fr][colA]);
#pragma unroll
      for (int ni = 0; ni < 4; ++ni)
        acc[mi][ni] = __builtin_amdgcn_mfma_f32_16x16x32_bf16(
            ah, bh[ni], acc[mi][ni], 0, 0, 0);
    }
    __syncthreads();
  }

  // fused dot with G (fp32 [M][ldg]); cols cc >= N guarded.
  float dot = 0.f;
#pragma unroll
  for (int mi = 0; mi < 8; ++mi)
#pragma unroll
    for (int ni = 0; ni < 4; ++ni) {
      int cc = n0 + wn * 64 + ni * 16 + fr;
      if (cc < N) {
        long long base =
            (long long)(m0 + wm * 128 + mi * 16 + fq * 4) * ldg + cc;
#pragma unroll
        for (int j = 0; j < 4; ++j)
          dot += acc[mi][ni][j] * G[base + (long long)j * ldg];
      }
    }
#pragma unroll
  for (int o = 32; o; o >>= 1) dot += __shfl_xor(dot, o);
  float* red = (float*)&tAh[0][0];  // LDS free after final barrier
  if (lane == 0) red[wave] = dot;
  __syncthreads();
  if (tid == 0)
    partial[bz * gridDim.x + b2] = red[0] + red[1] + red[2] + red[3];
}

// ---------------------------------------------------------------------------
// gemm0w: GEMM0 on the 256x128 structure (proven ~226 us). A = x fp32
// [32768][1025] (odd lda -> reg-staged), B = RT fp32. In-register h/r split,
// swizzled ds_write, split h/r output planes.
// ---------------------------------------------------------------------------
__global__ __launch_bounds__(256, 2) void gemm0w(
    const float* __restrict__ A, int lda, const float* __restrict__ B, int ldb,
    bf16* __restrict__ Ch, bf16* __restrict__ Cr, int ldc, int N, int K,
    int ntn) {
  __shared__ bf16 tAh[256][32], tAr[256][32], tBh[128][32], tBr[128][32];

  const int tid = threadIdx.x;
  const int lane = tid & 63, wave = tid >> 6;
  const int wm = wave & 1, wn = wave >> 1;
  const int fr = lane & 15, fq = lane >> 4;

  const int nwg = gridDim.x;
  const int q = nwg >> 3, r = nwg & 7;
  const int xcd = blockIdx.x & 7, o8 = blockIdx.x >> 3;
  const int b2 = (xcd < r ? xcd * (q + 1) : r * (q + 1) + (xcd - r) * q) + o8;
  const int tm = b2 / ntn, tn = b2 % ntn;
  const int m0 = tm * 256, n0 = tn * 128;

  const int row0 = tid >> 2, slot = tid & 3;
  const int wcol = ((slot ^ ((tid >> 3) & 3)) << 3);
  const int colA = ((fq ^ ((fr >> 1) & 3)) << 3);

  f32x4 acc[8][4] = {};
  const int nk = K >> 5;
  for (int kt = 0; kt < nk; ++kt) {
    const int k0 = kt << 5;
    f32x8a ra[4], rb[2];
#pragma unroll
    for (int p = 0; p < 4; ++p) {
      int row = row0 + p * 64;
      ra[p] = *reinterpret_cast<const f32x8a*>(
          A + (long long)(m0 + row) * lda + k0 + slot * 8);
    }
#pragma unroll
    for (int p = 0; p < 2; ++p) {
      int n = n0 + row0 + p * 64;
      n = n < N ? n : N - 1;
      rb[p] = *reinterpret_cast<const f32x8a*>(
          B + (long long)n * ldb + k0 + slot * 8);
    }
    __syncthreads();  // prior iter's frag reads complete
#pragma unroll
    for (int p = 0; p < 4; ++p) {
      int row = row0 + p * 64;
      bf16x8 vh, vr;
#pragma unroll
      for (int j = 0; j < 8; ++j) {
        float f = ra[p][j];
        bf16 h = (bf16)f;
        vh[j] = h;
        vr[j] = (bf16)(f - (float)h);
      }
      *reinterpret_cast<bf16x8*>(&tAh[row][wcol]) = vh;
      *reinterpret_cast<bf16x8*>(&tAr[row][wcol]) = vr;
    }
#pragma unroll
    for (int p = 0; p < 2; ++p) {
      int row = row0 + p * 64;
      bf16x8 vh, vr;
#pragma unroll
      for (int j = 0; j < 8; ++j) {
        float f = rb[p][j];
        bf16 h = (bf16)f;
        vh[j] = h;
        vr[j] = (bf16)(f - (float)h);
      }
      *reinterpret_cast<bf16x8*>(&tBh[row][wcol]) = vh;
      *reinterpret_cast<bf16x8*>(&tBr[row][wcol]) = vr;
    }
    __syncthreads();

    bf16x8 bh[4], br_[4];
#pragma unroll
    for (int i = 0; i < 4; ++i) {
      bh[i] = *reinterpret_cast<const bf16x8*>(&tBh[wn * 64 + i * 16 + fr][colA]);
      br_[i] = *reinterpret_cast<const bf16x8*>(&tBr[wn * 64 + i * 16 + fr][colA]);
    }
#pragma unroll
    for (int mi = 0; mi < 8; ++mi) {
      bf16x8 ah = *reinterpret_cast<const bf16x8*>(
          &tAh[wm * 128 + mi * 16 + fr][colA]);
      bf16x8 ar_ = *reinterpret_cast<const bf16x8*>(
          &tAr[wm * 128 + mi * 16 + fr][colA]);
#pragma unroll
      for (int ni = 0; ni < 4; ++ni)
        acc[mi][ni] = __builtin_amdgcn_mfma_f32_16x16x32_bf16(
            ah, bh[ni], acc[mi][ni], 0, 0, 0);
#pragma unroll
      for (int ni = 0; ni < 4; ++ni)
        acc[mi][ni] = __builtin_amdgcn_mfma_f32_16x16x32_bf16(
            ah, br_[ni], acc[mi][ni], 0, 0, 0);
#pragma unroll
      for (int ni = 0; ni < 4; ++ni)
        acc[mi][ni] = __builtin_amdgcn_mfma_f32_16x16x32_bf16(
            ar_, bh[ni], acc[mi][ni], 0, 0, 0);
    }
  }

#pragma unroll
  for (int mi = 0; mi < 8; ++mi)
#pragma unroll
    for (int ni = 0; ni < 4; ++ni) {
      int cc = n0 + wn * 64 + ni * 16 + fr;
      if (cc < N) {
        long long base =
            (long long)(m0 + wm * 128 + mi * 16 + fq * 4) * ldc + cc;
#pragma unroll
        for (int j = 0; j < 4; ++j) {
          float v = acc[mi][ni][j];
          bf16 h = (bf16)v;
          Ch[base + (long long)j * ldc] = h;
          Cr[base + (long long)j * ldc] = (bf16)(v - (float)h);
        }
      }
    }
}

// ---------------------------------------------------------------------------
template <int SPLIT>
__global__ __launch_bounds__(256) void transpose_tile(
    const float* __restrict__ src, int R, int Cc, float* __restrict__ df,
    bf16* __restrict__ dh, bf16* __restrict__ dr, int Nout, int outC,
    int ntk) {
  __shared__ float t[32][33];
  const int nt = blockIdx.x / ntk, kt = blockIdx.x % ntk;
  const int n0 = nt * 32, k0 = kt * 32;
  const int c = threadIdx.x & 31, r0 = threadIdx.x >> 5;
#pragma unroll
  for (int p = 0; p < 4; ++p) {
    int k = k0 + r0 + p * 8, n = n0 + c;
    t[r0 + p * 8][c] = (k < R && n < Cc) ? src[(long long)k * Cc + n] : 0.f;
  }
  __syncthreads();
#pragma unroll
  for (int p = 0; p < 4; ++p) {
    int n = n0 + r0 + p * 8, k = k0 + c;
    if (n < Nout && k < outC) {
      float v = t[c][r0 + p * 8];
      long long idx = (long long)n * outC + k;
      if constexpr (SPLIT) {
        bf16 h = (bf16)v;
        dh[idx] = h;
        dr[idx] = (bf16)(v - (float)h);
      } else {
        df[idx] = v;
      }
    }
  }
}

// Tiled bf16 transpose (h-plane only): dst[b][e][t] = src[b][t][e].
__global__ __launch_bounds__(256) void transpose_h(
    const ushort* __restrict__ sh, ushort* __restrict__ dh) {
  __shared__ ushort lh[32][33];
  const long long b = blockIdx.y;
  const int et = blockIdx.x >> 5, tt = blockIdx.x & 31;
  const int e0 = et * 32, t0 = tt * 32;
  const int c = threadIdx.x & 31, r0 = threadIdx.x >> 5;
  const ushort* sh_b = sh + b * 1024 * 1056;
#pragma unroll
  for (int p = 0; p < 4; ++p) {
    int t = t0 + r0 + p * 8;
    lh[r0 + p * 8][c] = sh_b[(long long)t * 1056 + e0 + c];
  }
  __syncthreads();
  ushort* dh_b = dh + b * 1056 * 1024;
#pragma unroll
  for (int p = 0; p < 4; ++p) {
    int e = e0 + r0 + p * 8;
    dh_b[(long long)e * 1024 + t0 + c] = lh[c][r0 + p * 8];
  }
}

// Generic pad (no transpose) -> split h/r planes.
__global__ __launch_bounds__(256) void pad_split_g(
    const float* __restrict__ src, int R, int Cc, bf16* __restrict__ dh,
    bf16* __restrict__ dr, long long total, int outC) {
  long long idx = (long long)blockIdx.x * 256 + threadIdx.x;
  if (idx >= total) return;
  int n = (int)(idx / outC), k = (int)(idx % outC);
  float v = (n < R && k < Cc) ? src[(long long)n * Cc + k] : 0.f;
  bf16 h = (bf16)v;
  dh[idx] = h;
  dr[idx] = (bf16)(v - (float)h);
}

__global__ __launch_bounds__(256) void fixup_y_split(bf16* __restrict__ Yh,
                                                     bf16* __restrict__ Yr,
                                                     const float* __restrict__ x) {
  int row = blockIdx.x * 256 + threadIdx.x;
  if (row < 32768) {
    float v = x[(long long)row * 1025 + 1024];
    bf16 h = (bf16)v;
    long long base = (long long)row * 1056;
    Yh[base + 1024] = h;
    Yr[base + 1024] = (bf16)(v - (float)h);
#pragma unroll
    for (int c = 1025; c < 1056; ++c) {
      Yh[base + c] = (bf16)0.f;
      Yr[base + c] = (bf16)0.f;
    }
  }
}

// Vectorized row softmax over 1024 fp32 logits -> split h/r bf16 prob planes
// written IN-PLACE into the Plog buffer (Ph = first 1024 bf16 of each 4KB
// row, Pr = next 1024; ld 2048). float4 loads (16B/lane), ushort4 stores.
// wr == 0: skip the residual plane (layer-3 fast path).
__global__ __launch_bounds__(256) void softmax_split(float* __restrict__ Plog,
                                                     int wr) {
  long long row = blockIdx.x;
  float* p = Plog + row * 1024;
  int tid = threadIdx.x;
  f32x4 v = *reinterpret_cast<const f32x4*>(p + tid * 4);
  float m = fmaxf(fmaxf(v[0], v[1]), fmaxf(v[2], v[3]));
#pragma unroll
  for (int o = 32; o; o >>= 1) m = fmaxf(m, __shfl_xor(m, o));
  __shared__ float sm[4];
  if ((tid & 63) == 0) sm[tid >> 6] = m;
  __syncthreads();
  m = fmaxf(fmaxf(sm[0], sm[1]), fmaxf(sm[2], sm[3]));
  float s = 0.f;
  f32x4 e;
#pragma unroll
  for (int j = 0; j < 4; ++j) {
    e[j] = __expf(v[j] - m);
    s += e[j];
  }
#pragma unroll
  for (int o = 32; o; o >>= 1) s += __shfl_xor(s, o);
  __shared__ float ss[4];
  if ((tid & 63) == 0) ss[tid >> 6] = s;
  __syncthreads();
  s = ss[0] + ss[1] + ss[2] + ss[3];
  float inv = 1.0f / s;
  bf16* ph = reinterpret_cast<bf16*>(p);  // row bytes [0, 2KB)
  bf16* pr = ph + 1024;                   // row bytes [2KB, 4KB)
  union { bf16 h[4]; ushort4 u; } th, tr;
#pragma unroll
  for (int j = 0; j < 4; ++j) {
    float pv = e[j] * inv;
    bf16 h = (bf16)pv;
    th.h[j] = h;
    tr.h[j] = (bf16)(pv - (float)h);
  }
  *reinterpret_cast<ushort4*>(ph + tid * 4) = th.u;
  if (wr) *reinterpret_cast<ushort4*>(pr + tid * 4) = tr.u;
}

__global__ void finalize_k(const float* __restrict__ partial,
                           const float* __restrict__ offs,
                           float* __restrict__ out, int per_b) {
  int b = threadIdx.x;
  if (b < 32) {
    float s = 0.f;
    for (int i = 0; i < per_b; ++i) s += partial[b * per_b + i];
    out[b] = s + offs[0];
  }
}

// ---------------------------------------------------------------------------

extern "C" void kernel_launch(void* const* d_in, const int* in_sizes, int n_in,
                              void* d_out, int out_size, void* d_ws,
                              size_t ws_size, hipStream_t stream) {
  const float* x = (const float*)d_in[0];
  const float* Wq[3] = {(const float*)d_in[1], (const float*)d_in[4],
                        (const float*)d_in[7]};
  const float* Wk[3] = {(const float*)d_in[2], (const float*)d_in[5],
                        (const float*)d_in[8]};
  const float* Wv[3] = {(const float*)d_in[3], (const float*)d_in[6],
                        (const float*)d_in[9]};
  const float* R = (const float*)d_in[10];
  const float* coef = (const float*)d_in[11];
  const float* offs = (const float*)d_in[12];
  float* out = (float*)d_out;

  // CB=16: every producer->consumer working set fits the 256MB L3
  // (P 67 + vT 69 + out 69 MB), unlike CB=32 (272MB+ -> thrash, 4x refetch
  // measured in round 18). Grids still fill the machine (>=512 blocks).
  const int CB = (ws_size >= (size_t)335000000ULL) ? 16 : 8;
  const int NCH = 32 / CB;

  char* ws = (char*)d_ws;
  size_t off = 0;
  auto alloc = [&](size_t bytes) -> void* {
    void* p = ws + off;
    off = (off + bytes + 255) & ~(size_t)255;
    return p;
  };
  bf16* Yh = (bf16*)alloc(32768LL * 1056 * 2);
  bf16* Yr = (bf16*)alloc(32768LL * 1056 * 2);
  bf16* qkh = (bf16*)alloc(32768LL * 128 * 2);
  bf16* qkr = (bf16*)alloc(32768LL * 128 * 2);
  float* Plog = (float*)alloc((long long)CB * 1024 * 1024 * 4);
  bf16* Ph = (bf16*)Plog;  // aliased planes, ld 2048
  bf16* Pr = Ph + 1024;
  bf16* vTh = (bf16*)alloc((long long)CB * 1056 * 1024 * 2);  // also a2T (L3)
  bf16* vTr = (bf16*)alloc((long long)CB * 1056 * 1024 * 2);
  float* RT = (float*)alloc(1024LL * 1024 * 4);
  bf16 *WqkTh[3], *WqkTr[3], *WvTh[3], *WvTr[3];
  for (int i = 0; i < 3; ++i) {
    WqkTh[i] = (bf16*)alloc(128LL * 1056 * 2);
    WqkTr[i] = (bf16*)alloc(128LL * 1056 * 2);
    WvTh[i] = (bf16*)alloc(1056LL * 1056 * 2);
    WvTr[i] = (bf16*)alloc(1056LL * 1056 * 2);
  }
  bf16* coefh = (bf16*)alloc(1024LL * 1056 * 2);
  bf16* coefr = (bf16*)alloc(1024LL * 1056 * 2);
  float* G = (float*)alloc(1024LL * 1056 * 4);
  float* partial = (float*)alloc(32 * 36 * 4);

  // ---- weight prep ----
  transpose_tile<0><<<32 * 32, 256, 0, stream>>>(R, 1024, 1024, RT, nullptr,
                                                 nullptr, 1024, 1024, 32);
  for (int l = 0; l < 3; ++l) {
    transpose_tile<1><<<33 * 2, 256, 0, stream>>>(
        Wq[l], 1025, 64, nullptr, WqkTh[l], WqkTr[l], 64, 1056, 33);
    transpose_tile<1><<<33 * 2, 256, 0, stream>>>(
        Wk[l], 1025, 64, nullptr, WqkTh[l] + 64 * 1056, WqkTr[l] + 64 * 1056,
        64, 1056, 33);
    if (l < 2) {
      transpose_tile<1><<<33 * 33, 256, 0, stream>>>(
          Wv[l], 1025, 1025, nullptr, WvTh[l], WvTr[l], 1056, 1056, 33);
    } else {
      // layer 3 needs only G = coef @ Wv3^T -> BT-form B = Wv3 UNTRANSPOSED
      pad_split_g<<<4356, 256, 0, stream>>>(Wv[l], 1025, 1025, WvTh[l],
                                            WvTr[l], 1056LL * 1056, 1056);
    }
  }
  pad_split_g<<<4224, 256, 0, stream>>>(coef, 1024, 1025, coefh, coefr,
                                        1024LL * 1056, 1056);
  gemm_hr<0><<<dim3(72, 1), 256, 0, stream>>>(
      coefh, coefr, 1056, 0, WvTh[2], WvTr[2], 1056, 0, G, nullptr, nullptr,
      1056, 0, 1056, 1056, 9);

  // ---- y = x[:, :1024] @ R -> split Y planes (256x128 structure) ----
  gemm0w<<<dim3(1024, 1), 256, 0, stream>>>(x, 1025, RT, 1024, Yh, Yr, 1056,
                                            1024, 1024, 8);
  fixup_y_split<<<128, 256, 0, stream>>>(Yh, Yr, x);

  for (int l = 0; l < 3; ++l) {
    // q|k fused over FULL batch: [32768,128] = Y @ [Wq|Wk]  (grid 256: fill)
    gemm_hr<1><<<dim3(256, 1), 256, 0, stream>>>(
        Yh, Yr, 1056, 0, WqkTh[l], WqkTr[l], 1056, 0, nullptr, qkh, qkr, 128,
        0, 128, 1056, 1);
    for (int ch = 0; ch < NCH; ++ch) {
      const long long b0 = (long long)ch * CB;
      bf16* Ych = Yh + b0 * 1024 * 1056;
      bf16* Ycr = Yr + b0 * 1024 * 1056;
      bf16* qkch = qkh + b0 * 1024 * 128;
      bf16* qkcr = qkr + b0 * 1024 * 128;
      if (l < 2) {
        // vT[b] = SWAPPED BT-GEMM: A = WvT (weights, L2-resident, M=1056),
        // B = Y_b -> vT written directly (coalesced OUT=1). tn-major (-5)
        // co-locates Y panel sharers on one XCD.
        gemm_hr2<1><<<dim3(40, CB), 256, 0, stream>>>(
            WvTh[l], WvTr[l], 1056, 0, Ych, Ycr, 1056, 1024LL * 1056, nullptr,
            vTh, vTr, 1024, 1056LL * 1024, 1056, 1024, 1056, -5);
      } else {
        // layer 3: a2T[b] = Y_b^T (h-plane only; dot kernel is 1-pass)
        transpose_h<<<dim3(33 * 32, CB), 256, 0, stream>>>(
            (const ushort*)Ych, (ushort*)vTh);
      }
      // logits[b] = q_b @ k_b^T -> fp32 Plog
      gemm_hr2<0><<<dim3(32, CB), 256, 0, stream>>>(
          qkch, qkcr, 128, 1024LL * 128, qkch + 64, qkcr + 64, 128,
          1024LL * 128, Plog, nullptr, nullptr, 1024, 1024LL * 1024, 1024,
          1024, 64, 8);
      // in-place softmax: Plog rows -> Ph|Pr bf16 planes (ld 2048)
      softmax_split<<<CB * 1024, 256, 0, stream>>>(Plog, l < 2 ? 1 : 0);
      if (l < 2) {
        // a[b] = P_b @ v_b -> writes Y_b in place (P ld 2048, aliased)
        gemm_hr2<1><<<dim3(36, CB), 256, 0, stream>>>(
            Ph, Pr, 2048, 1024LL * 2048, vTh, vTr, 1024, 1056LL * 1024,
            nullptr, Ych, Ycr, 1056, 1024LL * 1056, 1024, 1056, 1024, 9);
      } else {
        // out_b partials = sum( (Ph3_b @ a2h_b) .* G )  (1-pass fast path)
        gemm_dot1<<<dim3(36, CB), 256, 0, stream>>>(
            Ph, 2048, 1024LL * 2048, vTh, 1024, 1056LL * 1024, 1056, 1024, 9,
            G, 1056, partial + b0 * 36);
      }
    }
  }

  finalize_k<<<1, 32, 0, stream>>>(partial, offs, out, 36);
}

// Round 20
// 1872.238 us; speedup vs baseline: 1.1411x; 1.1411x over previous
//
#include <hip/hip_runtime.h>
#include <hip/hip_bf16.h>
#include <stdint.h>

typedef __bf16 bf16;
typedef __bf16 bf16x8 __attribute__((ext_vector_type(8)));
typedef float f32x4 __attribute__((ext_vector_type(4)));
typedef float f32x8u __attribute__((ext_vector_type(8)));
typedef f32x8u f32x8a __attribute__((aligned(4)));

// async global->LDS, 16B per lane; LDS dest = wave-uniform base + lane*16
__device__ __forceinline__ void gl16(const void* g, void* lds) {
  __builtin_amdgcn_global_load_lds(
      (const __attribute__((address_space(1))) void*)g,
      (__attribute__((address_space(3))) void*)lds, 16, 0, 0);
}

// ---------------------------------------------------------------------------
// gemm_hr: 128x128 tile, 1-phase, 16x16x32 (proven). Split-storage emulated-
// fp32 GEMM, BT form: C[m,n] = sum_k A[m,k]*B[n,k], acc += AhBh + AhBr + ArBh.
// Used for qk (grid 256 = good fill) and the small G GEMM.
// OUT: 0 fp32, 1 h/r planes.
// ---------------------------------------------------------------------------
template <int OUT>
__global__ __launch_bounds__(256) void gemm_hr(
    const bf16* __restrict__ Ah, const bf16* __restrict__ Ar, int lda,
    long long sA_, const bf16* __restrict__ Bh, const bf16* __restrict__ Br,
    int ldb, long long sB_, float* __restrict__ Cf, bf16* __restrict__ Ch,
    bf16* __restrict__ Cr, int ldc, long long sC_, int N, int K, int ntn) {
  __shared__ bf16 tAh[128][32], tAr[128][32], tBh[128][32], tBr[128][32];

  const int tid = threadIdx.x;
  const int lane = tid & 63, wave = tid >> 6;
  const int wm = wave & 1, wn = wave >> 1;
  const int fr = lane & 15, fq = lane >> 4;

  const long long bz = blockIdx.y;
  Ah += bz * sA_;
  Ar += bz * sA_;
  Bh += bz * sB_;
  Br += bz * sB_;

  const int cpx = gridDim.x >> 3;
  const int b2 = (blockIdx.x & 7) * cpx + (blockIdx.x >> 3);
  const int tm = b2 / ntn, tn = b2 % ntn;
  const int m0 = tm * 128, n0 = tn * 128;

  const int c0 = wave * 128 + lane;
  const int colsw = (((c0 & 3) ^ ((c0 >> 3) & 3)) << 3);
  const int rA0 = m0 + (c0 >> 2);
  int rB0 = n0 + (c0 >> 2), rB1 = rB0 + 16;
  rB0 = rB0 < N ? rB0 : N - 1;
  rB1 = rB1 < N ? rB1 : N - 1;
  const long long offA0 = (long long)rA0 * lda + colsw;
  const long long offA1 = offA0 + (long long)16 * lda;
  const long long offB0 = (long long)rB0 * ldb + colsw;
  const long long offB1 = (long long)rB1 * ldb + colsw;

  char* dAh = (char*)&tAh[0][0] + wave * 2048;
  char* dAr = (char*)&tAr[0][0] + wave * 2048;
  char* dBh = (char*)&tBh[0][0] + wave * 2048;
  char* dBr = (char*)&tBr[0][0] + wave * 2048;

  const int colA = ((fq ^ ((fr >> 1) & 3)) << 3);

  f32x4 acc[4][4] = {};
  const int nk = K >> 5;
  for (int kt = 0; kt < nk; ++kt) {
    const int k0 = kt << 5;
    gl16(Ah + offA0 + k0, dAh);
    gl16(Ah + offA1 + k0, dAh + 1024);
    gl16(Ar + offA0 + k0, dAr);
    gl16(Ar + offA1 + k0, dAr + 1024);
    gl16(Bh + offB0 + k0, dBh);
    gl16(Bh + offB1 + k0, dBh + 1024);
    gl16(Br + offB0 + k0, dBr);
    gl16(Br + offB1 + k0, dBr + 1024);
    __syncthreads();  // drains vmcnt(0): LDS tiles ready

    bf16x8 ah[4], ar_[4], bh[4], br_[4];
#pragma unroll
    for (int i = 0; i < 4; ++i) {
      ah[i] = *reinterpret_cast<const bf16x8*>(&tAh[wm * 64 + i * 16 + fr][colA]);
      ar_[i] = *reinterpret_cast<const bf16x8*>(&tAr[wm * 64 + i * 16 + fr][colA]);
      bh[i] = *reinterpret_cast<const bf16x8*>(&tBh[wn * 64 + i * 16 + fr][colA]);
      br_[i] = *reinterpret_cast<const bf16x8*>(&tBr[wn * 64 + i * 16 + fr][colA]);
    }
#pragma unroll
    for (int mi = 0; mi < 4; ++mi)
#pragma unroll
      for (int ni = 0; ni < 4; ++ni)
        acc[mi][ni] = __builtin_amdgcn_mfma_f32_16x16x32_bf16(
            ah[mi], bh[ni], acc[mi][ni], 0, 0, 0);
#pragma unroll
    for (int mi = 0; mi < 4; ++mi)
#pragma unroll
      for (int ni = 0; ni < 4; ++ni)
        acc[mi][ni] = __builtin_amdgcn_mfma_f32_16x16x32_bf16(
            ah[mi], br_[ni], acc[mi][ni], 0, 0, 0);
#pragma unroll
    for (int mi = 0; mi < 4; ++mi)
#pragma unroll
      for (int ni = 0; ni < 4; ++ni)
        acc[mi][ni] = __builtin_amdgcn_mfma_f32_16x16x32_bf16(
            ar_[mi], bh[ni], acc[mi][ni], 0, 0, 0);
    __syncthreads();
  }

  if constexpr (OUT == 0) {
    float* C = Cf + bz * sC_;
#pragma unroll
    for (int mi = 0; mi < 4; ++mi)
#pragma unroll
      for (int ni = 0; ni < 4; ++ni) {
        int cc = n0 + wn * 64 + ni * 16 + fr;
        if (cc < N) {
          long long base = (long long)(m0 + wm * 64 + mi * 16 + fq * 4) * ldc + cc;
#pragma unroll
          for (int j = 0; j < 4; ++j) C[base + (long long)j * ldc] = acc[mi][ni][j];
        }
      }
  } else {
    bf16* CH = Ch + bz * sC_;
    bf16* CR = Cr + bz * sC_;
#pragma unroll
    for (int mi = 0; mi < 4; ++mi)
#pragma unroll
      for (int ni = 0; ni < 4; ++ni) {
        int cc = n0 + wn * 64 + ni * 16 + fr;
        if (cc < N) {
          long long base = (long long)(m0 + wm * 64 + mi * 16 + fq * 4) * ldc + cc;
#pragma unroll
          for (int j = 0; j < 4; ++j) {
            float v = acc[mi][ni][j];
            bf16 h = (bf16)v;
            CH[base + (long long)j * ldc] = h;
            CR[base + (long long)j * ldc] = (bf16)(v - (float)h);
          }
        }
      }
  }
}

// ---------------------------------------------------------------------------
// gemm_hr2: 256x128 tile, 4 waves of 128x64, 1-phase, 16x16x32 (proven).
// M param: A rows (staging reads clamped to M-1; stores guarded) -> supports
// padded-M launches (vT swap, M=1056). ntn > 0: tm-major (tm=b2/ntn);
// ntn < 0: tn-major with |ntn| = ntm (tm=b2%ntm) — co-locates B-panel
// sharers on one XCD when A is small/L2-resident.
// OUT: 0 fp32 C; 1 h/r C; 2 h/r C transposed.
// XCD swizzle: bijective for ANY gridDim.x (m204 form).
// ---------------------------------------------------------------------------
template <int OUT>
__global__ __launch_bounds__(256, 2) void gemm_hr2(
    const bf16* __restrict__ Ah, const bf16* __restrict__ Ar, int lda,
    long long sA_, const bf16* __restrict__ Bh, const bf16* __restrict__ Br,
    int ldb, long long sB_, float* __restrict__ Cf, bf16* __restrict__ Ch,
    bf16* __restrict__ Cr, int ldc, long long sC_, int M, int N, int K,
    int ntn) {
  __shared__ bf16 tAh[256][32], tAr[256][32], tBh[128][32], tBr[128][32];

  const int tid = threadIdx.x;
  const int lane = tid & 63, wave = tid >> 6;
  const int wm = wave & 1, wn = wave >> 1;
  const int fr = lane & 15, fq = lane >> 4;

  const long long bz = blockIdx.y;
  Ah += bz * sA_;
  Ar += bz * sA_;
  Bh += bz * sB_;
  Br += bz * sB_;

  // bijective XCD swizzle for arbitrary nwg (m204)
  const int nwg = gridDim.x;
  const int q = nwg >> 3, r = nwg & 7;
  const int xcd = blockIdx.x & 7, o8 = blockIdx.x >> 3;
  const int b2 = (xcd < r ? xcd * (q + 1) : r * (q + 1) + (xcd - r) * q) + o8;
  int tm, tn;
  if (ntn > 0) {
    tm = b2 / ntn;
    tn = b2 % ntn;
  } else {
    const int ntm = -ntn;
    tn = b2 / ntm;
    tm = b2 % ntm;
  }
  const int m0 = tm * 256, n0 = tn * 128;

  const int cA = wave * 64 + lane;
  const int colsw = (((cA & 3) ^ ((cA >> 3) & 3)) << 3);
  const int rA = cA >> 2;  // 0..63
  long long offAj[4];
#pragma unroll
  for (int j = 0; j < 4; ++j) {
    int rAj = m0 + rA + j * 64;
    rAj = rAj < M ? rAj : M - 1;  // clamp padded-M reads
    offAj[j] = (long long)rAj * lda + colsw;
  }
  int rB0 = n0 + rA, rB1 = n0 + rA + 64;
  rB0 = rB0 < N ? rB0 : N - 1;
  rB1 = rB1 < N ? rB1 : N - 1;
  const long long offB0 = (long long)rB0 * ldb + colsw;
  const long long offB1 = (long long)rB1 * ldb + colsw;

  char* dAh = (char*)&tAh[0][0] + wave * 1024;
  char* dAr = (char*)&tAr[0][0] + wave * 1024;
  char* dBh = (char*)&tBh[0][0] + wave * 1024;
  char* dBr = (char*)&tBr[0][0] + wave * 1024;

  const int colA = ((fq ^ ((fr >> 1) & 3)) << 3);

  f32x4 acc[8][4] = {};
  const int nk = K >> 5;
  for (int kt = 0; kt < nk; ++kt) {
    const int k0 = kt << 5;
#pragma unroll
    for (int j = 0; j < 4; ++j) {
      gl16(Ah + offAj[j] + k0, dAh + j * 4096);
      gl16(Ar + offAj[j] + k0, dAr + j * 4096);
    }
    gl16(Bh + offB0 + k0, dBh);
    gl16(Bh + offB1 + k0, dBh + 4096);
    gl16(Br + offB0 + k0, dBr);
    gl16(Br + offB1 + k0, dBr + 4096);
    __syncthreads();  // drains vmcnt(0): tiles ready

    bf16x8 bh[4], br_[4];
#pragma unroll
    for (int i = 0; i < 4; ++i) {
      bh[i] = *reinterpret_cast<const bf16x8*>(&tBh[wn * 64 + i * 16 + fr][colA]);
      br_[i] = *reinterpret_cast<const bf16x8*>(&tBr[wn * 64 + i * 16 + fr][colA]);
    }
#pragma unroll
    for (int mi = 0; mi < 8; ++mi) {
      bf16x8 ah = *reinterpret_cast<const bf16x8*>(
          &tAh[wm * 128 + mi * 16 + fr][colA]);
      bf16x8 ar_ = *reinterpret_cast<const bf16x8*>(
          &tAr[wm * 128 + mi * 16 + fr][colA]);
#pragma unroll
      for (int ni = 0; ni < 4; ++ni)
        acc[mi][ni] = __builtin_amdgcn_mfma_f32_16x16x32_bf16(
            ah, bh[ni], acc[mi][ni], 0, 0, 0);
#pragma unroll
      for (int ni = 0; ni < 4; ++ni)
        acc[mi][ni] = __builtin_amdgcn_mfma_f32_16x16x32_bf16(
            ah, br_[ni], acc[mi][ni], 0, 0, 0);
#pragma unroll
      for (int ni = 0; ni < 4; ++ni)
        acc[mi][ni] = __builtin_amdgcn_mfma_f32_16x16x32_bf16(
            ar_, bh[ni], acc[mi][ni], 0, 0, 0);
    }
    __syncthreads();  // protect LDS before next stage
  }

  if constexpr (OUT == 0) {
    float* C = Cf + bz * sC_;
#pragma unroll
    for (int mi = 0; mi < 8; ++mi)
#pragma unroll
      for (int ni = 0; ni < 4; ++ni) {
        int cc = n0 + wn * 64 + ni * 16 + fr;
        int gr = m0 + wm * 128 + mi * 16 + fq * 4;
        if (cc < N && gr < M) {
          long long base = (long long)gr * ldc + cc;
#pragma unroll
          for (int j = 0; j < 4; ++j) C[base + (long long)j * ldc] = acc[mi][ni][j];
        }
      }
  } else if constexpr (OUT == 1) {
    bf16* CH = Ch + bz * sC_;
    bf16* CR = Cr + bz * sC_;
#pragma unroll
    for (int mi = 0; mi < 8; ++mi)
#pragma unroll
      for (int ni = 0; ni < 4; ++ni) {
        int cc = n0 + wn * 64 + ni * 16 + fr;
        int gr = m0 + wm * 128 + mi * 16 + fq * 4;
        if (cc < N && gr < M) {
          long long base = (long long)gr * ldc + cc;
#pragma unroll
          for (int j = 0; j < 4; ++j) {
            float v = acc[mi][ni][j];
            bf16 h = (bf16)v;
            CH[base + (long long)j * ldc] = h;
            CR[base + (long long)j * ldc] = (bf16)(v - (float)h);
          }
        }
      }
  } else {
    bf16* CH = Ch + bz * sC_;
    bf16* CR = Cr + bz * sC_;
#pragma unroll
    for (int mi = 0; mi < 8; ++mi)
#pragma unroll
      for (int ni = 0; ni < 4; ++ni) {
        int cc = n0 + wn * 64 + ni * 16 + fr;
        int mr = m0 + wm * 128 + mi * 16 + fq * 4;
        if (cc < N && mr < M) {
          union { bf16 h[4]; uint2 u; } th, tr;
#pragma unroll
          for (int j = 0; j < 4; ++j) {
            float v = acc[mi][ni][j];
            bf16 h = (bf16)v;
            th.h[j] = h;
            tr.h[j] = (bf16)(v - (float)h);
          }
          *reinterpret_cast<uint2*>(CH + (long long)cc * ldc + mr) = th.u;
          *reinterpret_cast<uint2*>(CR + (long long)cc * ldc + mr) = tr.u;
        }
      }
  }
}

// ---------------------------------------------------------------------------
// gemm_dot1: layer-3 fast path. 1-pass h-plane GEMM (Ph3 @ a2Th^T) with
// fused dot-with-G epilogue -> one scalar per block.
// ---------------------------------------------------------------------------
__global__ __launch_bounds__(256, 2) void gemm_dot1(
    const bf16* __restrict__ Ah, int lda, long long sA_,
    const bf16* __restrict__ Bh, int ldb, long long sB_, int N, int K,
    int ntn, const float* __restrict__ G, int ldg,
    float* __restrict__ partial) {
  __shared__ bf16 tAh[256][32], tBh[128][32];

  const int tid = threadIdx.x;
  const int lane = tid & 63, wave = tid >> 6;
  const int wm = wave & 1, wn = wave >> 1;
  const int fr = lane & 15, fq = lane >> 4;

  const long long bz = blockIdx.y;
  Ah += bz * sA_;
  Bh += bz * sB_;

  const int nwg = gridDim.x;
  const int q = nwg >> 3, r = nwg & 7;
  const int xcd = blockIdx.x & 7, o8 = blockIdx.x >> 3;
  const int b2 = (xcd < r ? xcd * (q + 1) : r * (q + 1) + (xcd - r) * q) + o8;
  const int tm = b2 / ntn, tn = b2 % ntn;
  const int m0 = tm * 256, n0 = tn * 128;

  const int cA = wave * 64 + lane;
  const int colsw = (((cA & 3) ^ ((cA >> 3) & 3)) << 3);
  const int rA = cA >> 2;
  const long long offA = (long long)(m0 + rA) * lda + colsw;
  const long long strA = (long long)64 * lda;
  int rB0 = n0 + rA, rB1 = n0 + rA + 64;
  rB0 = rB0 < N ? rB0 : N - 1;
  rB1 = rB1 < N ? rB1 : N - 1;
  const long long offB0 = (long long)rB0 * ldb + colsw;
  const long long offB1 = (long long)rB1 * ldb + colsw;

  char* dAh = (char*)&tAh[0][0] + wave * 1024;
  char* dBh = (char*)&tBh[0][0] + wave * 1024;

  const int colA = ((fq ^ ((fr >> 1) & 3)) << 3);

  f32x4 acc[8][4] = {};
  const int nk = K >> 5;
  for (int kt = 0; kt < nk; ++kt) {
    const int k0 = kt << 5;
#pragma unroll
    for (int j = 0; j < 4; ++j) gl16(Ah + offA + j * strA + k0, dAh + j * 4096);
    gl16(Bh + offB0 + k0, dBh);
    gl16(Bh + offB1 + k0, dBh + 4096);
    __syncthreads();

    bf16x8 bh[4];
#pragma unroll
    for (int i = 0; i < 4; ++i)
      bh[i] = *reinterpret_cast<const bf16x8*>(&tBh[wn * 64 + i * 16 + fr][colA]);
#pragma unroll
    for (int mi = 0; mi < 8; ++mi) {
      bf16x8 ah = *reinterpret_cast<const bf16x8*>(
          &tAh[wm * 128 + mi * 16 + fr][colA]);
#pragma unroll
      for (int ni = 0; ni < 4; ++ni)
        acc[mi][ni] = __builtin_amdgcn_mfma_f32_16x16x32_bf16(
            ah, bh[ni], acc[mi][ni], 0, 0, 0);
    }
    __syncthreads();
  }

  // fused dot with G (fp32 [M][ldg]); cols cc >= N guarded.
  float dot = 0.f;
#pragma unroll
  for (int mi = 0; mi < 8; ++mi)
#pragma unroll
    for (int ni = 0; ni < 4; ++ni) {
      int cc = n0 + wn * 64 + ni * 16 + fr;
      if (cc < N) {
        long long base =
            (long long)(m0 + wm * 128 + mi * 16 + fq * 4) * ldg + cc;
#pragma unroll
        for (int j = 0; j < 4; ++j)
          dot += acc[mi][ni][j] * G[base + (long long)j * ldg];
      }
    }
#pragma unroll
  for (int o = 32; o; o >>= 1) dot += __shfl_xor(dot, o);
  float* red = (float*)&tAh[0][0];  // LDS free after final barrier
  if (lane == 0) red[wave] = dot;
  __syncthreads();
  if (tid == 0)
    partial[bz * gridDim.x + b2] = red[0] + red[1] + red[2] + red[3];
}

// ---------------------------------------------------------------------------
// gemm0w: GEMM0 on the 256x128 structure (proven ~226 us). A = x fp32
// [32768][1025] (odd lda -> reg-staged), B = RT fp32. In-register h/r split,
// swizzled ds_write, split h/r output planes.
// ---------------------------------------------------------------------------
__global__ __launch_bounds__(256, 2) void gemm0w(
    const float* __restrict__ A, int lda, const float* __restrict__ B, int ldb,
    bf16* __restrict__ Ch, bf16* __restrict__ Cr, int ldc, int N, int K,
    int ntn) {
  __shared__ bf16 tAh[256][32], tAr[256][32], tBh[128][32], tBr[128][32];

  const int tid = threadIdx.x;
  const int lane = tid & 63, wave = tid >> 6;
  const int wm = wave & 1, wn = wave >> 1;
  const int fr = lane & 15, fq = lane >> 4;

  const int nwg = gridDim.x;
  const int q = nwg >> 3, r = nwg & 7;
  const int xcd = blockIdx.x & 7, o8 = blockIdx.x >> 3;
  const int b2 = (xcd < r ? xcd * (q + 1) : r * (q + 1) + (xcd - r) * q) + o8;
  const int tm = b2 / ntn, tn = b2 % ntn;
  const int m0 = tm * 256, n0 = tn * 128;

  const int row0 = tid >> 2, slot = tid & 3;
  const int wcol = ((slot ^ ((tid >> 3) & 3)) << 3);
  const int colA = ((fq ^ ((fr >> 1) & 3)) << 3);

  f32x4 acc[8][4] = {};
  const int nk = K >> 5;
  for (int kt = 0; kt < nk; ++kt) {
    const int k0 = kt << 5;
    f32x8a ra[4], rb[2];
#pragma unroll
    for (int p = 0; p < 4; ++p) {
      int row = row0 + p * 64;
      ra[p] = *reinterpret_cast<const f32x8a*>(
          A + (long long)(m0 + row) * lda + k0 + slot * 8);
    }
#pragma unroll
    for (int p = 0; p < 2; ++p) {
      int n = n0 + row0 + p * 64;
      n = n < N ? n : N - 1;
      rb[p] = *reinterpret_cast<const f32x8a*>(
          B + (long long)n * ldb + k0 + slot * 8);
    }
    __syncthreads();  // prior iter's frag reads complete
#pragma unroll
    for (int p = 0; p < 4; ++p) {
      int row = row0 + p * 64;
      bf16x8 vh, vr;
#pragma unroll
      for (int j = 0; j < 8; ++j) {
        float f = ra[p][j];
        bf16 h = (bf16)f;
        vh[j] = h;
        vr[j] = (bf16)(f - (float)h);
      }
      *reinterpret_cast<bf16x8*>(&tAh[row][wcol]) = vh;
      *reinterpret_cast<bf16x8*>(&tAr[row][wcol]) = vr;
    }
#pragma unroll
    for (int p = 0; p < 2; ++p) {
      int row = row0 + p * 64;
      bf16x8 vh, vr;
#pragma unroll
      for (int j = 0; j < 8; ++j) {
        float f = rb[p][j];
        bf16 h = (bf16)f;
        vh[j] = h;
        vr[j] = (bf16)(f - (float)h);
      }
      *reinterpret_cast<bf16x8*>(&tBh[row][wcol]) = vh;
      *reinterpret_cast<bf16x8*>(&tBr[row][wcol]) = vr;
    }
    __syncthreads();

    bf16x8 bh[4], br_[4];
#pragma unroll
    for (int i = 0; i < 4; ++i) {
      bh[i] = *reinterpret_cast<const bf16x8*>(&tBh[wn * 64 + i * 16 + fr][colA]);
      br_[i] = *reinterpret_cast<const bf16x8*>(&tBr[wn * 64 + i * 16 + fr][colA]);
    }
#pragma unroll
    for (int mi = 0; mi < 8; ++mi) {
      bf16x8 ah = *reinterpret_cast<const bf16x8*>(
          &tAh[wm * 128 + mi * 16 + fr][colA]);
      bf16x8 ar_ = *reinterpret_cast<const bf16x8*>(
          &tAr[wm * 128 + mi * 16 + fr][colA]);
#pragma unroll
      for (int ni = 0; ni < 4; ++ni)
        acc[mi][ni] = __builtin_amdgcn_mfma_f32_16x16x32_bf16(
            ah, bh[ni], acc[mi][ni], 0, 0, 0);
#pragma unroll
      for (int ni = 0; ni < 4; ++ni)
        acc[mi][ni] = __builtin_amdgcn_mfma_f32_16x16x32_bf16(
            ah, br_[ni], acc[mi][ni], 0, 0, 0);
#pragma unroll
      for (int ni = 0; ni < 4; ++ni)
        acc[mi][ni] = __builtin_amdgcn_mfma_f32_16x16x32_bf16(
            ar_, bh[ni], acc[mi][ni], 0, 0, 0);
    }
  }

#pragma unroll
  for (int mi = 0; mi < 8; ++mi)
#pragma unroll
    for (int ni = 0; ni < 4; ++ni) {
      int cc = n0 + wn * 64 + ni * 16 + fr;
      if (cc < N) {
        long long base =
            (long long)(m0 + wm * 128 + mi * 16 + fq * 4) * ldc + cc;
#pragma unroll
        for (int j = 0; j < 4; ++j) {
          float v = acc[mi][ni][j];
          bf16 h = (bf16)v;
          Ch[base + (long long)j * ldc] = h;
          Cr[base + (long long)j * ldc] = (bf16)(v - (float)h);
        }
      }
    }
}

// ---------------------------------------------------------------------------
template <int SPLIT>
__global__ __launch_bounds__(256) void transpose_tile(
    const float* __restrict__ src, int R, int Cc, float* __restrict__ df,
    bf16* __restrict__ dh, bf16* __restrict__ dr, int Nout, int outC,
    int ntk) {
  __shared__ float t[32][33];
  const int nt = blockIdx.x / ntk, kt = blockIdx.x % ntk;
  const int n0 = nt * 32, k0 = kt * 32;
  const int c = threadIdx.x & 31, r0 = threadIdx.x >> 5;
#pragma unroll
  for (int p = 0; p < 4; ++p) {
    int k = k0 + r0 + p * 8, n = n0 + c;
    t[r0 + p * 8][c] = (k < R && n < Cc) ? src[(long long)k * Cc + n] : 0.f;
  }
  __syncthreads();
#pragma unroll
  for (int p = 0; p < 4; ++p) {
    int n = n0 + r0 + p * 8, k = k0 + c;
    if (n < Nout && k < outC) {
      float v = t[c][r0 + p * 8];
      long long idx = (long long)n * outC + k;
      if constexpr (SPLIT) {
        bf16 h = (bf16)v;
        dh[idx] = h;
        dr[idx] = (bf16)(v - (float)h);
      } else {
        df[idx] = v;
      }
    }
  }
}

// Tiled bf16 transpose (h-plane only): dst[b][e][t] = src[b][t][e].
__global__ __launch_bounds__(256) void transpose_h(
    const ushort* __restrict__ sh, ushort* __restrict__ dh) {
  __shared__ ushort lh[32][33];
  const long long b = blockIdx.y;
  const int et = blockIdx.x >> 5, tt = blockIdx.x & 31;
  const int e0 = et * 32, t0 = tt * 32;
  const int c = threadIdx.x & 31, r0 = threadIdx.x >> 5;
  const ushort* sh_b = sh + b * 1024 * 1056;
#pragma unroll
  for (int p = 0; p < 4; ++p) {
    int t = t0 + r0 + p * 8;
    lh[r0 + p * 8][c] = sh_b[(long long)t * 1056 + e0 + c];
  }
  __syncthreads();
  ushort* dh_b = dh + b * 1056 * 1024;
#pragma unroll
  for (int p = 0; p < 4; ++p) {
    int e = e0 + r0 + p * 8;
    dh_b[(long long)e * 1024 + t0 + c] = lh[c][r0 + p * 8];
  }
}

// Generic pad (no transpose) -> split h/r planes.
__global__ __launch_bounds__(256) void pad_split_g(
    const float* __restrict__ src, int R, int Cc, bf16* __restrict__ dh,
    bf16* __restrict__ dr, long long total, int outC) {
  long long idx = (long long)blockIdx.x * 256 + threadIdx.x;
  if (idx >= total) return;
  int n = (int)(idx / outC), k = (int)(idx % outC);
  float v = (n < R && k < Cc) ? src[(long long)n * Cc + k] : 0.f;
  bf16 h = (bf16)v;
  dh[idx] = h;
  dr[idx] = (bf16)(v - (float)h);
}

__global__ __launch_bounds__(256) void fixup_y_split(bf16* __restrict__ Yh,
                                                     bf16* __restrict__ Yr,
                                                     const float* __restrict__ x) {
  int row = blockIdx.x * 256 + threadIdx.x;
  if (row < 32768) {
    float v = x[(long long)row * 1025 + 1024];
    bf16 h = (bf16)v;
    long long base = (long long)row * 1056;
    Yh[base + 1024] = h;
    Yr[base + 1024] = (bf16)(v - (float)h);
#pragma unroll
    for (int c = 1025; c < 1056; ++c) {
      Yh[base + c] = (bf16)0.f;
      Yr[base + c] = (bf16)0.f;
    }
  }
}

// Vectorized row softmax over 1024 fp32 logits -> split h/r bf16 prob planes
// written IN-PLACE into the Plog buffer (Ph = first 1024 bf16 of each 4KB
// row, Pr = next 1024; ld 2048). float4 loads (16B/lane), ushort4 stores.
// wr == 0: skip the residual plane (layer-3 fast path).
__global__ __launch_bounds__(256) void softmax_split(float* __restrict__ Plog,
                                                     int wr) {
  long long row = blockIdx.x;
  float* p = Plog + row * 1024;
  int tid = threadIdx.x;
  f32x4 v = *reinterpret_cast<const f32x4*>(p + tid * 4);
  float m = fmaxf(fmaxf(v[0], v[1]), fmaxf(v[2], v[3]));
#pragma unroll
  for (int o = 32; o; o >>= 1) m = fmaxf(m, __shfl_xor(m, o));
  __shared__ float sm[4];
  if ((tid & 63) == 0) sm[tid >> 6] = m;
  __syncthreads();
  m = fmaxf(fmaxf(sm[0], sm[1]), fmaxf(sm[2], sm[3]));
  float s = 0.f;
  f32x4 e;
#pragma unroll
  for (int j = 0; j < 4; ++j) {
    e[j] = __expf(v[j] - m);
    s += e[j];
  }
#pragma unroll
  for (int o = 32; o; o >>= 1) s += __shfl_xor(s, o);
  __shared__ float ss[4];
  if ((tid & 63) == 0) ss[tid >> 6] = s;
  __syncthreads();
  s = ss[0] + ss[1] + ss[2] + ss[3];
  float inv = 1.0f / s;
  bf16* ph = reinterpret_cast<bf16*>(p);  // row bytes [0, 2KB)
  bf16* pr = ph + 1024;                   // row bytes [2KB, 4KB)
  union { bf16 h[4]; ushort4 u; } th, tr;
#pragma unroll
  for (int j = 0; j < 4; ++j) {
    float pv = e[j] * inv;
    bf16 h = (bf16)pv;
    th.h[j] = h;
    tr.h[j] = (bf16)(pv - (float)h);
  }
  *reinterpret_cast<ushort4*>(ph + tid * 4) = th.u;
  if (wr) *reinterpret_cast<ushort4*>(pr + tid * 4) = tr.u;
}

__global__ void finalize_k(const float* __restrict__ partial,
                           const float* __restrict__ offs,
                           float* __restrict__ out, int per_b) {
  int b = threadIdx.x;
  if (b < 32) {
    float s = 0.f;
    for (int i = 0; i < per_b; ++i) s += partial[b * per_b + i];
    out[b] = s + offs[0];
  }
}

// ---------------------------------------------------------------------------

extern "C" void kernel_launch(void* const* d_in, const int* in_sizes, int n_in,
                              void* d_out, int out_size, void* d_ws,
                              size_t ws_size, hipStream_t stream) {
  const float* x = (const float*)d_in[0];
  const float* Wq[3] = {(const float*)d_in[1], (const float*)d_in[4],
                        (const float*)d_in[7]};
  const float* Wk[3] = {(const float*)d_in[2], (const float*)d_in[5],
                        (const float*)d_in[8]};
  const float* Wv[3] = {(const float*)d_in[3], (const float*)d_in[6],
                        (const float*)d_in[9]};
  const float* R = (const float*)d_in[10];
  const float* coef = (const float*)d_in[11];
  const float* offs = (const float*)d_in[12];
  float* out = (float*)d_out;

  // CB=32 preferred (A/B proven: 1875 us vs CB=16's 2136 — launch/tail
  // overhead dominates; 580MB refetch runs at 2.7TB/s and hides under MFMA).
  const int CB = (ws_size >= (size_t)470000000ULL)
                     ? 32
                     : ((ws_size >= (size_t)335000000ULL) ? 16 : 8);
  const int NCH = 32 / CB;

  char* ws = (char*)d_ws;
  size_t off = 0;
  auto alloc = [&](size_t bytes) -> void* {
    void* p = ws + off;
    off = (off + bytes + 255) & ~(size_t)255;
    return p;
  };
  bf16* Yh = (bf16*)alloc(32768LL * 1056 * 2);
  bf16* Yr = (bf16*)alloc(32768LL * 1056 * 2);
  bf16* qkh = (bf16*)alloc(32768LL * 128 * 2);
  bf16* qkr = (bf16*)alloc(32768LL * 128 * 2);
  float* Plog = (float*)alloc((long long)CB * 1024 * 1024 * 4);
  bf16* Ph = (bf16*)Plog;  // aliased planes, ld 2048
  bf16* Pr = Ph + 1024;
  bf16* vTh = (bf16*)alloc((long long)CB * 1056 * 1024 * 2);  // also a2T (L3)
  bf16* vTr = (bf16*)alloc((long long)CB * 1056 * 1024 * 2);
  float* RT = (float*)alloc(1024LL * 1024 * 4);
  bf16 *WqkTh[3], *WqkTr[3], *WvTh[3], *WvTr[3];
  for (int i = 0; i < 3; ++i) {
    WqkTh[i] = (bf16*)alloc(128LL * 1056 * 2);
    WqkTr[i] = (bf16*)alloc(128LL * 1056 * 2);
    WvTh[i] = (bf16*)alloc(1056LL * 1056 * 2);
    WvTr[i] = (bf16*)alloc(1056LL * 1056 * 2);
  }
  bf16* coefh = (bf16*)alloc(1024LL * 1056 * 2);
  bf16* coefr = (bf16*)alloc(1024LL * 1056 * 2);
  float* G = (float*)alloc(1024LL * 1056 * 4);
  float* partial = (float*)alloc(32 * 36 * 4);

  // ---- weight prep ----
  transpose_tile<0><<<32 * 32, 256, 0, stream>>>(R, 1024, 1024, RT, nullptr,
                                                 nullptr, 1024, 1024, 32);
  for (int l = 0; l < 3; ++l) {
    transpose_tile<1><<<33 * 2, 256, 0, stream>>>(
        Wq[l], 1025, 64, nullptr, WqkTh[l], WqkTr[l], 64, 1056, 33);
    transpose_tile<1><<<33 * 2, 256, 0, stream>>>(
        Wk[l], 1025, 64, nullptr, WqkTh[l] + 64 * 1056, WqkTr[l] + 64 * 1056,
        64, 1056, 33);
    if (l < 2) {
      transpose_tile<1><<<33 * 33, 256, 0, stream>>>(
          Wv[l], 1025, 1025, nullptr, WvTh[l], WvTr[l], 1056, 1056, 33);
    } else {
      // layer 3 needs only G = coef @ Wv3^T -> BT-form B = Wv3 UNTRANSPOSED
      pad_split_g<<<4356, 256, 0, stream>>>(Wv[l], 1025, 1025, WvTh[l],
                                            WvTr[l], 1056LL * 1056, 1056);
    }
  }
  pad_split_g<<<4224, 256, 0, stream>>>(coef, 1024, 1025, coefh, coefr,
                                        1024LL * 1056, 1056);
  gemm_hr<0><<<dim3(72, 1), 256, 0, stream>>>(
      coefh, coefr, 1056, 0, WvTh[2], WvTr[2], 1056, 0, G, nullptr, nullptr,
      1056, 0, 1056, 1056, 9);

  // ---- y = x[:, :1024] @ R -> split Y planes (256x128 structure) ----
  gemm0w<<<dim3(1024, 1), 256, 0, stream>>>(x, 1025, RT, 1024, Yh, Yr, 1056,
                                            1024, 1024, 8);
  fixup_y_split<<<128, 256, 0, stream>>>(Yh, Yr, x);

  for (int l = 0; l < 3; ++l) {
    // q|k fused over FULL batch: [32768,128] = Y @ [Wq|Wk]  (grid 256: fill)
    gemm_hr<1><<<dim3(256, 1), 256, 0, stream>>>(
        Yh, Yr, 1056, 0, WqkTh[l], WqkTr[l], 1056, 0, nullptr, qkh, qkr, 128,
        0, 128, 1056, 1);
    for (int ch = 0; ch < NCH; ++ch) {
      const long long b0 = (long long)ch * CB;
      bf16* Ych = Yh + b0 * 1024 * 1056;
      bf16* Ycr = Yr + b0 * 1024 * 1056;
      bf16* qkch = qkh + b0 * 1024 * 128;
      bf16* qkcr = qkr + b0 * 1024 * 128;
      if (l < 2) {
        // vT[b] = SWAPPED BT-GEMM: A = WvT (weights, L2-resident, M=1056),
        // B = Y_b -> vT written directly (coalesced OUT=1). tn-major (-5)
        // co-locates Y panel sharers on one XCD.
        gemm_hr2<1><<<dim3(40, CB), 256, 0, stream>>>(
            WvTh[l], WvTr[l], 1056, 0, Ych, Ycr, 1056, 1024LL * 1056, nullptr,
            vTh, vTr, 1024, 1056LL * 1024, 1056, 1024, 1056, -5);
      } else {
        // layer 3: a2T[b] = Y_b^T (h-plane only; dot kernel is 1-pass)
        transpose_h<<<dim3(33 * 32, CB), 256, 0, stream>>>(
            (const ushort*)Ych, (ushort*)vTh);
      }
      // logits[b] = q_b @ k_b^T -> fp32 Plog
      gemm_hr2<0><<<dim3(32, CB), 256, 0, stream>>>(
          qkch, qkcr, 128, 1024LL * 128, qkch + 64, qkcr + 64, 128,
          1024LL * 128, Plog, nullptr, nullptr, 1024, 1024LL * 1024, 1024,
          1024, 64, 8);
      // in-place softmax: Plog rows -> Ph|Pr bf16 planes (ld 2048)
      softmax_split<<<CB * 1024, 256, 0, stream>>>(Plog, l < 2 ? 1 : 0);
      if (l < 2) {
        // a[b] = P_b @ v_b -> writes Y_b in place (P ld 2048, aliased)
        gemm_hr2<1><<<dim3(36, CB), 256, 0, stream>>>(
            Ph, Pr, 2048, 1024LL * 2048, vTh, vTr, 1024, 1056LL * 1024,
            nullptr, Ych, Ycr, 1056, 1024LL * 1056, 1024, 1056, 1024, 9);
      } else {
        // out_b partials = sum( (Ph3_b @ a2h_b) .* G )  (1-pass fast path)
        gemm_dot1<<<dim3(36, CB), 256, 0, stream>>>(
            Ph, 2048, 1024LL * 2048, vTh, 1024, 1056LL * 1024, 1056, 1024, 9,
            G, 1056, partial + b0 * 36);
      }
    }
  }

  finalize_k<<<1, 32, 0, stream>>>(partial, offs, out, 36);
}